// Round 9
// baseline (295.570 us; speedup 1.0000x reference)
//
#include <hip/hip_runtime.h>

typedef unsigned short u16;
typedef unsigned int u32;

static __device__ __forceinline__ float lrelu(float x) { return x >= 0.f ? x : 0.2f * x; }

static __device__ __forceinline__ u16 f2bf(float f) {
    u32 u = __float_as_uint(f);
    u += 0x7FFF + ((u >> 16) & 1);
    return (u16)(u >> 16);
}
static __device__ __forceinline__ float bflo(u32 u) { return __uint_as_float(u << 16); }
static __device__ __forceinline__ float bfhi(u32 u) { return __uint_as_float(u & 0xffff0000u); }

// 128->16 matvec across one wave: lane holds features (2*lane, 2*lane+1) = (f0,f1).
// Returns class ((lane>>2)&15)'s sum (valid where (lane&3)==0).
// Exchange-halves reduction, 17 shfl, all named registers (no arrays -> no scratch).
static __device__ __forceinline__ float fc_reduce16(float f0, float f1, int lane,
                                                    const float4* __restrict__ fW4) {
    float4 w00 = fW4[(2 * lane) * 4 + 0], w01 = fW4[(2 * lane) * 4 + 1];
    float4 w02 = fW4[(2 * lane) * 4 + 2], w03 = fW4[(2 * lane) * 4 + 3];
    float4 w10 = fW4[(2 * lane + 1) * 4 + 0], w11 = fW4[(2 * lane + 1) * 4 + 1];
    float4 w12 = fW4[(2 * lane + 1) * 4 + 2], w13 = fW4[(2 * lane + 1) * 4 + 3];
    float4 q0, q1, q2, q3;
    q0.x = f0 * w00.x + f1 * w10.x; q0.y = f0 * w00.y + f1 * w10.y;
    q0.z = f0 * w00.z + f1 * w10.z; q0.w = f0 * w00.w + f1 * w10.w;
    q1.x = f0 * w01.x + f1 * w11.x; q1.y = f0 * w01.y + f1 * w11.y;
    q1.z = f0 * w01.z + f1 * w11.z; q1.w = f0 * w01.w + f1 * w11.w;
    q2.x = f0 * w02.x + f1 * w12.x; q2.y = f0 * w02.y + f1 * w12.y;
    q2.z = f0 * w02.z + f1 * w12.z; q2.w = f0 * w02.w + f1 * w12.w;
    q3.x = f0 * w03.x + f1 * w13.x; q3.y = f0 * w03.y + f1 * w13.y;
    q3.z = f0 * w03.z + f1 * w13.z; q3.w = f0 * w03.w + f1 * w13.w;
    bool h5 = (lane & 32) != 0, h4 = (lane & 16) != 0;
    bool h3 = (lane & 8) != 0, h2 = (lane & 4) != 0;
    float4 s0, s1, k0, k1;
    s0.x = h5 ? q0.x : q2.x; s0.y = h5 ? q0.y : q2.y;
    s0.z = h5 ? q0.z : q2.z; s0.w = h5 ? q0.w : q2.w;
    s1.x = h5 ? q1.x : q3.x; s1.y = h5 ? q1.y : q3.y;
    s1.z = h5 ? q1.z : q3.z; s1.w = h5 ? q1.w : q3.w;
    s0.x = __shfl_xor(s0.x, 32); s0.y = __shfl_xor(s0.y, 32);
    s0.z = __shfl_xor(s0.z, 32); s0.w = __shfl_xor(s0.w, 32);
    s1.x = __shfl_xor(s1.x, 32); s1.y = __shfl_xor(s1.y, 32);
    s1.z = __shfl_xor(s1.z, 32); s1.w = __shfl_xor(s1.w, 32);
    k0.x = h5 ? q2.x : q0.x; k0.y = h5 ? q2.y : q0.y;
    k0.z = h5 ? q2.z : q0.z; k0.w = h5 ? q2.w : q0.w;
    k1.x = h5 ? q3.x : q1.x; k1.y = h5 ? q3.y : q1.y;
    k1.z = h5 ? q3.z : q1.z; k1.w = h5 ? q3.w : q1.w;
    float4 a0, a1;
    a0.x = k0.x + s0.x; a0.y = k0.y + s0.y; a0.z = k0.z + s0.z; a0.w = k0.w + s0.w;
    a1.x = k1.x + s1.x; a1.y = k1.y + s1.y; a1.z = k1.z + s1.z; a1.w = k1.w + s1.w;
    float4 sB, kB;
    sB.x = h4 ? a0.x : a1.x; sB.y = h4 ? a0.y : a1.y;
    sB.z = h4 ? a0.z : a1.z; sB.w = h4 ? a0.w : a1.w;
    sB.x = __shfl_xor(sB.x, 16); sB.y = __shfl_xor(sB.y, 16);
    sB.z = __shfl_xor(sB.z, 16); sB.w = __shfl_xor(sB.w, 16);
    kB.x = h4 ? a1.x : a0.x; kB.y = h4 ? a1.y : a0.y;
    kB.z = h4 ? a1.z : a0.z; kB.w = h4 ? a1.w : a0.w;
    float4 b;
    b.x = kB.x + sB.x; b.y = kB.y + sB.y; b.z = kB.z + sB.z; b.w = kB.w + sB.w;
    float sCx = h3 ? b.x : b.z, sCy = h3 ? b.y : b.w;
    sCx = __shfl_xor(sCx, 8); sCy = __shfl_xor(sCy, 8);
    float kCx = h3 ? b.z : b.x, kCy = h3 ? b.w : b.y;
    float c2x = kCx + sCx, c2y = kCy + sCy;
    float sD = h2 ? c2x : c2y;
    sD = __shfl_xor(sD, 4);
    float kD = h2 ? c2y : c2x;
    float r = kD + sD;
    r += __shfl_xor(r, 1);
    r += __shfl_xor(r, 2);
    return r;
}

// ---- GEMM: Hb = X @ W (bf16 out) + fused a_s/a_d; full graph then group graph ----
__global__ __launch_bounds__(256) void gemm_both_kernel(
        const float* __restrict__ Xf, const float* __restrict__ Wf,
        const float* __restrict__ asf, const float* __restrict__ adf,
        u16* __restrict__ Hbf, float* __restrict__ as_f, float* __restrict__ ad_f, int N,
        const float* __restrict__ Xg, const float* __restrict__ Wg,
        const float* __restrict__ asg, const float* __restrict__ adg,
        u16* __restrict__ Hbg, float* __restrict__ as_g, float* __restrict__ ad_g, int G,
        int nbFull) {
    const float* X; const float* W; const float* av; const float* dv;
    u16* Hb; float* as_out; float* ad_out; int n_lim; long base;
    if (blockIdx.x < nbFull) {
        X = Xf; W = Wf; av = asf; dv = adf; Hb = Hbf; as_out = as_f; ad_out = ad_f;
        n_lim = N; base = (long)blockIdx.x * 32;
    } else {
        X = Xg; W = Wg; av = asg; dv = adg; Hb = Hbg; as_out = as_g; ad_out = ad_g;
        n_lim = G; base = (long)(blockIdx.x - nbFull) * 32;
    }
    __shared__ float Ws[64 * 128];
    __shared__ float Xs[32 * 128];
    int tid = threadIdx.x;
    float4* Ws4 = (float4*)Ws;
    float4* Xs4 = (float4*)Xs;
    const float4* X4 = (const float4*)(X + base * 128);
    for (int i = tid; i < 1024; i += 256) {
        int r = i >> 5;
        Xs4[i] = (base + r < n_lim) ? X4[i] : make_float4(0.f, 0.f, 0.f, 0.f);
    }
    int fgrp = tid & 31;
    int n0 = (tid >> 5) * 4;
    float4 acc[4] = {};
    for (int half = 0; half < 2; ++half) {
        __syncthreads();
        const float4* W4 = (const float4*)(W + half * 64 * 128);
        for (int i = tid; i < 2048; i += 256) Ws4[i] = W4[i];
        __syncthreads();
        #pragma unroll 4
        for (int kk = 0; kk < 64; ++kk) {
            float4 w = Ws4[kk * 32 + fgrp];
            #pragma unroll
            for (int j = 0; j < 4; ++j) {
                float x = Xs[(n0 + j) * 128 + half * 64 + kk];
                acc[j].x += x * w.x; acc[j].y += x * w.y;
                acc[j].z += x * w.z; acc[j].w += x * w.w;
            }
        }
    }
    float4 as4 = ((const float4*)av)[fgrp];
    float4 ad4 = ((const float4*)dv)[fgrp];
    float ps[4], pd[4];
    #pragma unroll
    for (int j = 0; j < 4; ++j) {
        ps[j] = acc[j].x * as4.x + acc[j].y * as4.y + acc[j].z * as4.z + acc[j].w * as4.w;
        pd[j] = acc[j].x * ad4.x + acc[j].y * ad4.y + acc[j].z * ad4.z + acc[j].w * ad4.w;
    }
    #pragma unroll
    for (int off = 16; off; off >>= 1) {
        #pragma unroll
        for (int j = 0; j < 4; ++j) {
            ps[j] += __shfl_xor(ps[j], off);
            pd[j] += __shfl_xor(pd[j], off);
        }
    }
    if ((tid & 31) == 0) {
        #pragma unroll
        for (int j = 0; j < 4; ++j) {
            long n = base + n0 + j;
            if (n < n_lim) { as_out[n] = ps[j]; ad_out[n] = pd[j]; }
        }
    }
    #pragma unroll
    for (int j = 0; j < 4; ++j) {
        long n = base + n0 + j;
        if (n < n_lim) {
            ushort4 hv;
            hv.x = f2bf(acc[j].x); hv.y = f2bf(acc[j].y);
            hv.z = f2bf(acc[j].z); hv.w = f2bf(acc[j].w);
            ((ushort4*)(Hb + n * 128))[fgrp] = hv;
        }
    }
}

// ---------------- merged CSR build over both graphs ----------------
__global__ __launch_bounds__(256) void hist2_kernel(const int* __restrict__ efd, int E, int N,
                                                    const int* __restrict__ egd, int Eg, int G,
                                                    int Npad, int* __restrict__ deg) {
    int i = blockIdx.x * 256 + threadIdx.x;
    int totF = E + N;
    int tot = totF + Eg + G;
    if (i >= tot) return;
    int d;
    if (i < E) d = efd[i];
    else if (i < totF) d = i - E;
    else {
        int j = i - totF;
        d = Npad + ((j < Eg) ? egd[j] : (j - Eg));
    }
    atomicAdd(&deg[d], 1);
}

__global__ __launch_bounds__(256) void scan1_kernel(const int* __restrict__ deg, int n,
                                                    int* __restrict__ bsum) {
    __shared__ int s[256];
    int i = blockIdx.x * 256 + threadIdx.x;
    s[threadIdx.x] = (i < n) ? deg[i] : 0;
    __syncthreads();
    for (int off = 128; off; off >>= 1) {
        if (threadIdx.x < off) s[threadIdx.x] += s[threadIdx.x + off];
        __syncthreads();
    }
    if (threadIdx.x == 0) bsum[blockIdx.x] = s[0];
}

__global__ __launch_bounds__(256) void scan3_kernel(int* __restrict__ deg, int n, int nb,
                                                    const int* __restrict__ bsum,
                                                    int* __restrict__ offs, int Ltot) {
    __shared__ int sb[256];
    __shared__ int s[256];
    int t = threadIdx.x;
    sb[t] = (t < nb) ? bsum[t] : 0;
    __syncthreads();
    for (int off = 1; off < 256; off <<= 1) {
        int u = (t >= off) ? sb[t - off] : 0;
        __syncthreads();
        sb[t] += u;
        __syncthreads();
    }
    int blockOff = (blockIdx.x == 0) ? 0 : sb[blockIdx.x - 1];
    if (blockIdx.x == 0 && t == 0) offs[Ltot] = sb[nb - 1];

    int i = blockIdx.x * 256 + t;
    int v = (i < n) ? deg[i] : 0;
    s[t] = v;
    __syncthreads();
    for (int off = 1; off < 256; off <<= 1) {
        int u = (t >= off) ? s[t - off] : 0;
        __syncthreads();
        s[t] += u;
        __syncthreads();
    }
    if (i < n) {
        int excl = s[t] - v + blockOff;
        offs[i] = excl;
        deg[i] = excl;
    }
}

// placement: packed (src, e) per edge; e = exp(lrelu(a_s[src]+a_d[dst])) computed ONCE
__global__ __launch_bounds__(256) void place2_kernel(const int* __restrict__ efs,
                                                     const int* __restrict__ efd, int E, int N,
                                                     const int* __restrict__ egs,
                                                     const int* __restrict__ egd, int Eg, int G,
                                                     int Npad,
                                                     const float* __restrict__ a_s,
                                                     const float* __restrict__ a_d,
                                                     const float* __restrict__ a_sg,
                                                     const float* __restrict__ a_dg,
                                                     int* __restrict__ cursor,
                                                     int2* __restrict__ sepack) {
    int i = blockIdx.x * 256 + threadIdx.x;
    int totF = E + N;
    int tot = totF + Eg + G;
    if (i >= tot) return;
    int s, d, dcur;
    float av;
    if (i < totF) {
        if (i < E) { s = efs[i]; d = efd[i]; } else { s = d = i - E; }
        av = a_s[s] + a_d[d];
        dcur = d;
    } else {
        int j = i - totF;
        if (j < Eg) { s = egs[j]; d = egd[j]; } else { s = d = j - Eg; }
        av = a_sg[s] + a_dg[d];
        dcur = Npad + d;
    }
    float e = expf(lrelu(av));  // max-subtract skipped: alpha identical, no overflow
    int pos = atomicAdd(&cursor[dcur], 1);
    sepack[pos] = make_int2(s, __float_as_int(e));
}

// ---- pull: out = elu(sum(e*h)/sum(e) + bias).
// 16B/lane gather: lane = (edge subset l>>4, feature chunk l&15); one wave-instr
// gathers 4 rows (1KB). Pad edges carry e=0 -> processed harmlessly, no tail loop.
__global__ __launch_bounds__(256) void pull2_kernel(const u16* __restrict__ Hf,
                                                    const u16* __restrict__ Hg,
                                                    const int* __restrict__ offs,
                                                    const int2* __restrict__ sepack,
                                                    const float* __restrict__ bias_f,
                                                    const float* __restrict__ bias_g,
                                                    float* __restrict__ fx,
                                                    float* __restrict__ gx,
                                                    int N, int G, int Npad) {
    int gid = blockIdx.x * 256 + threadIdx.x;
    int w = gid >> 6, lane = gid & 63;
    const u16* H;
    const float* bias;
    float* out;
    int idx;
    if (w < N) {
        H = Hf; bias = bias_f; out = fx + (long)w * 128; idx = w;
    } else if (w < N + G) {
        int g = w - N;
        H = Hg; bias = bias_g; out = gx + (long)g * 128; idx = Npad + g;
    } else return;
    int beg = offs[idx], end = offs[idx + 1];
    const uint4* H16 = (const uint4*)H;  // one row = 16 uint4 (256B)
    int sub = lane >> 4;                 // edge subset 0..3
    int fc = lane & 15;                  // feature chunk (8 bf16)
    float a0 = 0.f, a1 = 0.f, a2 = 0.f, a3 = 0.f;
    float a4 = 0.f, a5 = 0.f, a6 = 0.f, a7 = 0.f;
    float ss = 0.f;
    for (int b = beg; b < end; b += 64) {
        int m = end - b;
        if (m > 64) m = 64;
        int2 se = (lane < m) ? sepack[b + lane] : make_int2(0, 0);  // pad: s=0, e=0
        int sl = se.x;
        float el = __int_as_float(se.y);
        int kend = (m + 3) & ~3;
        int k = 0;
        for (; k + 8 <= kend; k += 8) {  // 2 gathers in flight
            int s0 = __shfl(sl, k + sub);
            float e0 = __shfl(el, k + sub);
            int s1 = __shfl(sl, k + 4 + sub);
            float e1 = __shfl(el, k + 4 + sub);
            uint4 h0 = H16[(long)s0 * 16 + fc];
            uint4 h1 = H16[(long)s1 * 16 + fc];
            a0 += e0 * bflo(h0.x); a1 += e0 * bfhi(h0.x);
            a2 += e0 * bflo(h0.y); a3 += e0 * bfhi(h0.y);
            a4 += e0 * bflo(h0.z); a5 += e0 * bfhi(h0.z);
            a6 += e0 * bflo(h0.w); a7 += e0 * bfhi(h0.w);
            a0 += e1 * bflo(h1.x); a1 += e1 * bfhi(h1.x);
            a2 += e1 * bflo(h1.y); a3 += e1 * bfhi(h1.y);
            a4 += e1 * bflo(h1.z); a5 += e1 * bfhi(h1.z);
            a6 += e1 * bflo(h1.w); a7 += e1 * bfhi(h1.w);
            ss += e0 + e1;
        }
        if (k < kend) {  // one remaining group of 4
            int s0 = __shfl(sl, k + sub);
            float e0 = __shfl(el, k + sub);
            uint4 h0 = H16[(long)s0 * 16 + fc];
            a0 += e0 * bflo(h0.x); a1 += e0 * bfhi(h0.x);
            a2 += e0 * bflo(h0.y); a3 += e0 * bfhi(h0.y);
            a4 += e0 * bflo(h0.z); a5 += e0 * bfhi(h0.z);
            a6 += e0 * bflo(h0.w); a7 += e0 * bfhi(h0.w);
            ss += e0;
        }
    }
    // combine the 4 edge subsets (every lane ends with full totals for its chunk)
    a0 += __shfl_xor(a0, 16); a0 += __shfl_xor(a0, 32);
    a1 += __shfl_xor(a1, 16); a1 += __shfl_xor(a1, 32);
    a2 += __shfl_xor(a2, 16); a2 += __shfl_xor(a2, 32);
    a3 += __shfl_xor(a3, 16); a3 += __shfl_xor(a3, 32);
    a4 += __shfl_xor(a4, 16); a4 += __shfl_xor(a4, 32);
    a5 += __shfl_xor(a5, 16); a5 += __shfl_xor(a5, 32);
    a6 += __shfl_xor(a6, 16); a6 += __shfl_xor(a6, 32);
    a7 += __shfl_xor(a7, 16); a7 += __shfl_xor(a7, 32);
    ss += __shfl_xor(ss, 16); ss += __shfl_xor(ss, 32);
    if (lane < 16) {
        float inv = 1.f / ss;
        const float4* b4 = (const float4*)bias;
        float4 bA = b4[lane * 2], bB = b4[lane * 2 + 1];
        float4 oA, oB;
        oA.x = a0 * inv + bA.x; oA.y = a1 * inv + bA.y;
        oA.z = a2 * inv + bA.z; oA.w = a3 * inv + bA.w;
        oB.x = a4 * inv + bB.x; oB.y = a5 * inv + bB.y;
        oB.z = a6 * inv + bB.z; oB.w = a7 * inv + bB.w;
        oA.x = oA.x > 0.f ? oA.x : expm1f(oA.x);
        oA.y = oA.y > 0.f ? oA.y : expm1f(oA.y);
        oA.z = oA.z > 0.f ? oA.z : expm1f(oA.z);
        oA.w = oA.w > 0.f ? oA.w : expm1f(oA.w);
        oB.x = oB.x > 0.f ? oB.x : expm1f(oB.x);
        oB.y = oB.y > 0.f ? oB.y : expm1f(oB.y);
        oB.z = oB.z > 0.f ? oB.z : expm1f(oB.z);
        oB.w = oB.w > 0.f ? oB.w : expm1f(oB.w);
        float4* o4 = (float4*)out;
        o4[lane * 2] = oA;
        o4[lane * 2 + 1] = oB;
    }
}

// ---------------- adjacent-group sum (atomics; tiny graph) ----------------
__global__ __launch_bounds__(256) void adj_kernel(const int* __restrict__ gsrc,
                                                  const int* __restrict__ gdst, int Eg,
                                                  const float* __restrict__ gx,
                                                  float* __restrict__ adj_sum,
                                                  float* __restrict__ cnt) {
    int gid = blockIdx.x * 256 + threadIdx.x;
    int i = gid >> 6, lane = gid & 63;
    if (i >= Eg) return;
    int s = gsrc[i], d = gdst[i];
    float2 gv = ((const float2*)gx)[(long)d * 64 + lane];
    atomicAdd(&adj_sum[(long)s * 128 + 2 * lane], gv.x);
    atomicAdd(&adj_sum[(long)s * 128 + 2 * lane + 1], gv.y);
    if (lane == 0) atomicAdd(&cnt[s], 1.f);
}

// ---- final: dots + in-place updated + direct FC (named-reg fc_reduce16) ----
__global__ __launch_bounds__(256) void final3_kernel(const int* __restrict__ node_group,
                                                     const float* __restrict__ gx,
                                                     const float* __restrict__ adj_sum,
                                                     const float* __restrict__ cnt,
                                                     const float* __restrict__ fcW,
                                                     const float* __restrict__ fcb,
                                                     float* __restrict__ upd,
                                                     float* __restrict__ out, int N) {
    int gid = blockIdx.x * 256 + threadIdx.x;
    int n = gid >> 6, lane = gid & 63;
    if (n >= N) return;
    int g = node_group[n];
    float2 row = ((const float2*)upd)[(long)n * 64 + lane];
    float2 gf = ((const float2*)gx)[(long)g * 64 + lane];
    float inv_cnt = 1.f / fmaxf(cnt[g], 1.f);
    float2 as2 = ((const float2*)adj_sum)[(long)g * 64 + lane];
    float amx = as2.x * inv_cnt, amy = as2.y * inv_cnt;
    float pg = row.x * gf.x + row.y * gf.y;
    float pa = row.x * amx + row.y * amy;
    #pragma unroll
    for (int off = 32; off; off >>= 1) {
        pg += __shfl_xor(pg, off);
        pa += __shfl_xor(pa, off);
    }
    float ux = row.x + pg * gf.x + pa * amx;
    float uy = row.y + pg * gf.y + pa * amy;
    ((float2*)upd)[(long)n * 64 + lane] = make_float2(ux, uy);
    float r = fc_reduce16(ux, uy, lane, (const float4*)fcW);
    int cls = (lane >> 2) & 15;
    if ((lane & 3) == 0) out[(long)n * 16 + cls] = r + fcb[cls];
}

extern "C" void kernel_launch(void* const* d_in, const int* in_sizes, int n_in,
                              void* d_out, int out_size, void* d_ws, size_t ws_size,
                              hipStream_t stream) {
    const float* x_full = (const float*)d_in[0];
    const float* x_group = (const float*)d_in[1];
    const float* W_full = (const float*)d_in[2];
    const float* a_src_full = (const float*)d_in[3];
    const float* a_dst_full = (const float*)d_in[4];
    const float* bias_full = (const float*)d_in[5];
    const float* W_group = (const float*)d_in[6];
    const float* a_src_g = (const float*)d_in[7];
    const float* a_dst_g = (const float*)d_in[8];
    const float* bias_g = (const float*)d_in[9];
    const float* fc_W = (const float*)d_in[10];
    const float* fc_b = (const float*)d_in[11];
    const int* ef = (const int*)d_in[12];
    const int* eg = (const int*)d_in[13];
    const int* node_group = (const int*)d_in[14];

    int N = in_sizes[0] / 128;
    int G = in_sizes[1] / 128;
    int E = in_sizes[12] / 2;
    int Eg = in_sizes[13] / 2;
    const int* ef_src = ef;
    const int* ef_dst = ef + E;
    const int* eg_src = eg;
    const int* eg_dst = eg + Eg;

    int Npad = (N + 255) & ~255;
    int Ltot = Npad + G;
    int LtotPad = (Ltot + 255) & ~255;
    int totF = E + N;
    int tot = totF + Eg + G;

    float* out_cls = (float*)d_out;
    float* fx = out_cls + (long)N * 16;  // fullx_elu scratch, becomes `updated`

    char* w = (char*)d_ws;
    auto alloc = [&](size_t bytes) {
        char* p = w;
        w += (bytes + 255) & ~(size_t)255;
        return p;
    };
    u16* h_full = (u16*)alloc((size_t)N * 128 * 2);
    u16* h_g = (u16*)alloc((size_t)G * 128 * 2);
    float* a_s = (float*)alloc((size_t)N * 4);
    float* a_d = (float*)alloc((size_t)N * 4);
    float* a_sg = (float*)alloc((size_t)G * 4);
    float* a_dg = (float*)alloc((size_t)G * 4);
    float* gx = (float*)alloc((size_t)G * 128 * 4);
    // zero-init span: adj_sum, cnt, deg (contiguous, one memset)
    float* adj_sum = (float*)alloc((size_t)G * 128 * 4);
    float* cnt = (float*)alloc((size_t)G * 4);
    int* deg = (int*)alloc((size_t)LtotPad * 4);
    int* offs = (int*)alloc((size_t)(LtotPad + 1) * 4);
    int2* sepack = (int2*)alloc((size_t)tot * 8);
    int* bsum = (int*)alloc(256 * 4);

    size_t zero_span = (char*)(deg + LtotPad) - (char*)adj_sum;
    (void)hipMemsetAsync(adj_sum, 0, zero_span, stream);

    auto cdiv = [](int a, int b) { return (a + b - 1) / b; };

    // feature transforms + fused attention scalars (both graphs, one launch)
    int nbFull = cdiv(N, 32);
    gemm_both_kernel<<<nbFull + cdiv(G, 32), 256, 0, stream>>>(
        x_full, W_full, a_src_full, a_dst_full, h_full, a_s, a_d, N,
        x_group, W_group, a_src_g, a_dst_g, h_g, a_sg, a_dg, G, nbFull);

    // merged CSR build
    int nb = cdiv(Ltot, 256);
    hist2_kernel<<<cdiv(tot, 256), 256, 0, stream>>>(ef_dst, E, N, eg_dst, Eg, G, Npad, deg);
    scan1_kernel<<<nb, 256, 0, stream>>>(deg, Ltot, bsum);
    scan3_kernel<<<nb, 256, 0, stream>>>(deg, Ltot, nb, bsum, offs, Ltot);
    place2_kernel<<<cdiv(tot, 256), 256, 0, stream>>>(ef_src, ef_dst, E, N, eg_src, eg_dst,
                                                      Eg, G, Npad, a_s, a_d, a_sg, a_dg,
                                                      deg, sepack);

    // pull aggregation for both graphs
    pull2_kernel<<<cdiv((N + G) * 64, 256), 256, 0, stream>>>(h_full, h_g, offs, sepack,
                                                              bias_full, bias_g,
                                                              fx, gx, N, G, Npad);

    // adjacent-group sum -> final fused interaction + FC
    adj_kernel<<<cdiv(Eg * 64, 256), 256, 0, stream>>>(eg_src, eg_dst, Eg, gx, adj_sum, cnt);
    final3_kernel<<<cdiv(N * 64, 256), 256, 0, stream>>>(node_group, gx, adj_sum, cnt,
                                                         fc_W, fc_b, fx, out_cls, N);
}

// Round 10
// 282.546 us; speedup vs baseline: 1.0461x; 1.0461x over previous
//
#include <hip/hip_runtime.h>

typedef unsigned short u16;
typedef unsigned int u32;

static __device__ __forceinline__ float lrelu(float x) { return x >= 0.f ? x : 0.2f * x; }

static __device__ __forceinline__ u16 f2bf(float f) {
    u32 u = __float_as_uint(f);
    u += 0x7FFF + ((u >> 16) & 1);
    return (u16)(u >> 16);
}
static __device__ __forceinline__ float bflo(u32 u) { return __uint_as_float(u << 16); }
static __device__ __forceinline__ float bfhi(u32 u) { return __uint_as_float(u & 0xffff0000u); }

// 128->16 matvec across one wave (2 features/lane layout), 17 shfl, named regs.
static __device__ __forceinline__ float fc_reduce16(float f0, float f1, int lane,
                                                    const float4* __restrict__ fW4) {
    float4 w00 = fW4[(2 * lane) * 4 + 0], w01 = fW4[(2 * lane) * 4 + 1];
    float4 w02 = fW4[(2 * lane) * 4 + 2], w03 = fW4[(2 * lane) * 4 + 3];
    float4 w10 = fW4[(2 * lane + 1) * 4 + 0], w11 = fW4[(2 * lane + 1) * 4 + 1];
    float4 w12 = fW4[(2 * lane + 1) * 4 + 2], w13 = fW4[(2 * lane + 1) * 4 + 3];
    float4 q0, q1, q2, q3;
    q0.x = f0 * w00.x + f1 * w10.x; q0.y = f0 * w00.y + f1 * w10.y;
    q0.z = f0 * w00.z + f1 * w10.z; q0.w = f0 * w00.w + f1 * w10.w;
    q1.x = f0 * w01.x + f1 * w11.x; q1.y = f0 * w01.y + f1 * w11.y;
    q1.z = f0 * w01.z + f1 * w11.z; q1.w = f0 * w01.w + f1 * w11.w;
    q2.x = f0 * w02.x + f1 * w12.x; q2.y = f0 * w02.y + f1 * w12.y;
    q2.z = f0 * w02.z + f1 * w12.z; q2.w = f0 * w02.w + f1 * w12.w;
    q3.x = f0 * w03.x + f1 * w13.x; q3.y = f0 * w03.y + f1 * w13.y;
    q3.z = f0 * w03.z + f1 * w13.z; q3.w = f0 * w03.w + f1 * w13.w;
    bool h5 = (lane & 32) != 0, h4 = (lane & 16) != 0;
    bool h3 = (lane & 8) != 0, h2 = (lane & 4) != 0;
    float4 s0, s1, k0, k1;
    s0.x = h5 ? q0.x : q2.x; s0.y = h5 ? q0.y : q2.y;
    s0.z = h5 ? q0.z : q2.z; s0.w = h5 ? q0.w : q2.w;
    s1.x = h5 ? q1.x : q3.x; s1.y = h5 ? q1.y : q3.y;
    s1.z = h5 ? q1.z : q3.z; s1.w = h5 ? q1.w : q3.w;
    s0.x = __shfl_xor(s0.x, 32); s0.y = __shfl_xor(s0.y, 32);
    s0.z = __shfl_xor(s0.z, 32); s0.w = __shfl_xor(s0.w, 32);
    s1.x = __shfl_xor(s1.x, 32); s1.y = __shfl_xor(s1.y, 32);
    s1.z = __shfl_xor(s1.z, 32); s1.w = __shfl_xor(s1.w, 32);
    k0.x = h5 ? q2.x : q0.x; k0.y = h5 ? q2.y : q0.y;
    k0.z = h5 ? q2.z : q0.z; k0.w = h5 ? q2.w : q0.w;
    k1.x = h5 ? q3.x : q1.x; k1.y = h5 ? q3.y : q1.y;
    k1.z = h5 ? q3.z : q1.z; k1.w = h5 ? q3.w : q1.w;
    float4 a0, a1;
    a0.x = k0.x + s0.x; a0.y = k0.y + s0.y; a0.z = k0.z + s0.z; a0.w = k0.w + s0.w;
    a1.x = k1.x + s1.x; a1.y = k1.y + s1.y; a1.z = k1.z + s1.z; a1.w = k1.w + s1.w;
    float4 sB, kB;
    sB.x = h4 ? a0.x : a1.x; sB.y = h4 ? a0.y : a1.y;
    sB.z = h4 ? a0.z : a1.z; sB.w = h4 ? a0.w : a1.w;
    sB.x = __shfl_xor(sB.x, 16); sB.y = __shfl_xor(sB.y, 16);
    sB.z = __shfl_xor(sB.z, 16); sB.w = __shfl_xor(sB.w, 16);
    kB.x = h4 ? a1.x : a0.x; kB.y = h4 ? a1.y : a0.y;
    kB.z = h4 ? a1.z : a0.z; kB.w = h4 ? a1.w : a0.w;
    float4 b;
    b.x = kB.x + sB.x; b.y = kB.y + sB.y; b.z = kB.z + sB.z; b.w = kB.w + sB.w;
    float sCx = h3 ? b.x : b.z, sCy = h3 ? b.y : b.w;
    sCx = __shfl_xor(sCx, 8); sCy = __shfl_xor(sCy, 8);
    float kCx = h3 ? b.z : b.x, kCy = h3 ? b.w : b.y;
    float c2x = kCx + sCx, c2y = kCy + sCy;
    float sD = h2 ? c2x : c2y;
    sD = __shfl_xor(sD, 4);
    float kD = h2 ? c2y : c2x;
    float r = kD + sD;
    r += __shfl_xor(r, 1);
    r += __shfl_xor(r, 2);
    return r;
}

// ---- merged: GEMM (both graphs, blocks [0,nbGemm)) + edge histogram (rest) ----
__global__ __launch_bounds__(256) void gemm_hist_kernel(
        const float* __restrict__ Xf, const float* __restrict__ Wf,
        const float* __restrict__ asf, const float* __restrict__ adf,
        u16* __restrict__ Hbf, float* __restrict__ as_f, float* __restrict__ ad_f, int N,
        const float* __restrict__ Xg, const float* __restrict__ Wg,
        const float* __restrict__ asg, const float* __restrict__ adg,
        u16* __restrict__ Hbg, float* __restrict__ as_g, float* __restrict__ ad_g, int G,
        int nbFull, int nbGemm,
        const int* __restrict__ efd, int E, const int* __restrict__ egd, int Eg,
        int Npad, int* __restrict__ deg) {
    __shared__ float Ws[64 * 128];
    __shared__ float Xs[32 * 128];
    int tid = threadIdx.x;
    if (blockIdx.x >= nbGemm) {
        // histogram path (independent of GEMM inputs)
        int i = (blockIdx.x - nbGemm) * 256 + tid;
        int totF = E + N;
        int tot = totF + Eg + G;
        if (i >= tot) return;
        int d;
        if (i < E) d = efd[i];
        else if (i < totF) d = i - E;
        else {
            int j = i - totF;
            d = Npad + ((j < Eg) ? egd[j] : (j - Eg));
        }
        atomicAdd(&deg[d], 1);
        return;
    }
    const float* X; const float* W; const float* av; const float* dv;
    u16* Hb; float* as_out; float* ad_out; int n_lim; long base;
    if (blockIdx.x < nbFull) {
        X = Xf; W = Wf; av = asf; dv = adf; Hb = Hbf; as_out = as_f; ad_out = ad_f;
        n_lim = N; base = (long)blockIdx.x * 32;
    } else {
        X = Xg; W = Wg; av = asg; dv = adg; Hb = Hbg; as_out = as_g; ad_out = ad_g;
        n_lim = G; base = (long)(blockIdx.x - nbFull) * 32;
    }
    float4* Ws4 = (float4*)Ws;
    float4* Xs4 = (float4*)Xs;
    const float4* X4 = (const float4*)(X + base * 128);
    for (int i = tid; i < 1024; i += 256) {
        int r = i >> 5;
        Xs4[i] = (base + r < n_lim) ? X4[i] : make_float4(0.f, 0.f, 0.f, 0.f);
    }
    int fgrp = tid & 31;
    int n0 = (tid >> 5) * 4;
    float4 acc[4] = {};
    for (int half = 0; half < 2; ++half) {
        __syncthreads();
        const float4* W4 = (const float4*)(W + half * 64 * 128);
        for (int i = tid; i < 2048; i += 256) Ws4[i] = W4[i];
        __syncthreads();
        #pragma unroll 4
        for (int kk = 0; kk < 64; ++kk) {
            float4 w = Ws4[kk * 32 + fgrp];
            #pragma unroll
            for (int j = 0; j < 4; ++j) {
                float x = Xs[(n0 + j) * 128 + half * 64 + kk];
                acc[j].x += x * w.x; acc[j].y += x * w.y;
                acc[j].z += x * w.z; acc[j].w += x * w.w;
            }
        }
    }
    float4 as4 = ((const float4*)av)[fgrp];
    float4 ad4 = ((const float4*)dv)[fgrp];
    float ps[4], pd[4];
    #pragma unroll
    for (int j = 0; j < 4; ++j) {
        ps[j] = acc[j].x * as4.x + acc[j].y * as4.y + acc[j].z * as4.z + acc[j].w * as4.w;
        pd[j] = acc[j].x * ad4.x + acc[j].y * ad4.y + acc[j].z * ad4.z + acc[j].w * ad4.w;
    }
    #pragma unroll
    for (int off = 16; off; off >>= 1) {
        #pragma unroll
        for (int j = 0; j < 4; ++j) {
            ps[j] += __shfl_xor(ps[j], off);
            pd[j] += __shfl_xor(pd[j], off);
        }
    }
    if ((tid & 31) == 0) {
        #pragma unroll
        for (int j = 0; j < 4; ++j) {
            long n = base + n0 + j;
            if (n < n_lim) { as_out[n] = ps[j]; ad_out[n] = pd[j]; }
        }
    }
    #pragma unroll
    for (int j = 0; j < 4; ++j) {
        long n = base + n0 + j;
        if (n < n_lim) {
            ushort4 hv;
            hv.x = f2bf(acc[j].x); hv.y = f2bf(acc[j].y);
            hv.z = f2bf(acc[j].z); hv.w = f2bf(acc[j].w);
            ((ushort4*)(Hb + n * 128))[fgrp] = hv;
        }
    }
}

__global__ __launch_bounds__(256) void scan1_kernel(const int* __restrict__ deg, int n,
                                                    int* __restrict__ bsum) {
    __shared__ int s[256];
    int i = blockIdx.x * 256 + threadIdx.x;
    s[threadIdx.x] = (i < n) ? deg[i] : 0;
    __syncthreads();
    for (int off = 128; off; off >>= 1) {
        if (threadIdx.x < off) s[threadIdx.x] += s[threadIdx.x + off];
        __syncthreads();
    }
    if (threadIdx.x == 0) bsum[blockIdx.x] = s[0];
}

__global__ __launch_bounds__(256) void scan3_kernel(int* __restrict__ deg, int n, int nb,
                                                    const int* __restrict__ bsum,
                                                    int* __restrict__ offs, int Ltot) {
    __shared__ int sb[256];
    __shared__ int s[256];
    int t = threadIdx.x;
    sb[t] = (t < nb) ? bsum[t] : 0;
    __syncthreads();
    for (int off = 1; off < 256; off <<= 1) {
        int u = (t >= off) ? sb[t - off] : 0;
        __syncthreads();
        sb[t] += u;
        __syncthreads();
    }
    int blockOff = (blockIdx.x == 0) ? 0 : sb[blockIdx.x - 1];
    if (blockIdx.x == 0 && t == 0) offs[Ltot] = sb[nb - 1];

    int i = blockIdx.x * 256 + t;
    int v = (i < n) ? deg[i] : 0;
    s[t] = v;
    __syncthreads();
    for (int off = 1; off < 256; off <<= 1) {
        int u = (t >= off) ? s[t - off] : 0;
        __syncthreads();
        s[t] += u;
        __syncthreads();
    }
    if (i < n) {
        int excl = s[t] - v + blockOff;
        offs[i] = excl;
        deg[i] = excl;
    }
}

// placement: packed (src, e) per edge; e = exp(lrelu(a_s[src]+a_d[dst])) computed ONCE
__global__ __launch_bounds__(256) void place2_kernel(const int* __restrict__ efs,
                                                     const int* __restrict__ efd, int E, int N,
                                                     const int* __restrict__ egs,
                                                     const int* __restrict__ egd, int Eg, int G,
                                                     int Npad,
                                                     const float* __restrict__ a_s,
                                                     const float* __restrict__ a_d,
                                                     const float* __restrict__ a_sg,
                                                     const float* __restrict__ a_dg,
                                                     int* __restrict__ cursor,
                                                     int2* __restrict__ sepack) {
    int i = blockIdx.x * 256 + threadIdx.x;
    int totF = E + N;
    int tot = totF + Eg + G;
    if (i >= tot) return;
    int s, d, dcur;
    float av;
    if (i < totF) {
        if (i < E) { s = efs[i]; d = efd[i]; } else { s = d = i - E; }
        av = a_s[s] + a_d[d];
        dcur = d;
    } else {
        int j = i - totF;
        if (j < Eg) { s = egs[j]; d = egd[j]; } else { s = d = j - Eg; }
        av = a_sg[s] + a_dg[d];
        dcur = Npad + d;
    }
    float e = expf(lrelu(av));  // max-subtract skipped: alpha identical, no overflow
    int pos = atomicAdd(&cursor[dcur], 1);
    sepack[pos] = make_int2(s, __float_as_int(e));
}

// ---- pull: out = elu(sum(e*h)/sum(e) + bias); full waves also emit fxW = fx@fcW.
// 16B/lane gather (lane = edge subset l>>4, feature chunk l&15). Pad edges carry e=0.
// FC: after combine every lane holds its chunk's 8 totals; sub s computes classes 4s..4s+3.
__global__ __launch_bounds__(256) void pull2_kernel(const u16* __restrict__ Hf,
                                                    const u16* __restrict__ Hg,
                                                    const int* __restrict__ offs,
                                                    const int2* __restrict__ sepack,
                                                    const float* __restrict__ bias_f,
                                                    const float* __restrict__ bias_g,
                                                    const float* __restrict__ fcW,
                                                    float* __restrict__ fx,
                                                    float* __restrict__ gx,
                                                    float* __restrict__ fxW,
                                                    int N, int G, int Npad) {
    int gid = blockIdx.x * 256 + threadIdx.x;
    int w = gid >> 6, lane = gid & 63;
    const u16* H;
    const float* bias;
    float* out;
    int idx;
    bool isFull = (w < N);
    if (isFull) {
        H = Hf; bias = bias_f; out = fx + (long)w * 128; idx = w;
    } else if (w < N + G) {
        int g = w - N;
        H = Hg; bias = bias_g; out = gx + (long)g * 128; idx = Npad + g;
    } else return;
    int beg = offs[idx], end = offs[idx + 1];
    const uint4* H16 = (const uint4*)H;
    int sub = lane >> 4;
    int fc = lane & 15;
    float a0 = 0.f, a1 = 0.f, a2 = 0.f, a3 = 0.f;
    float a4 = 0.f, a5 = 0.f, a6 = 0.f, a7 = 0.f;
    float ss = 0.f;
    for (int b = beg; b < end; b += 64) {
        int m = end - b;
        if (m > 64) m = 64;
        int2 se = (lane < m) ? sepack[b + lane] : make_int2(0, 0);
        int sl = se.x;
        float el = __int_as_float(se.y);
        int kend = (m + 3) & ~3;
        int k = 0;
        for (; k + 8 <= kend; k += 8) {
            int s0 = __shfl(sl, k + sub);
            float e0 = __shfl(el, k + sub);
            int s1 = __shfl(sl, k + 4 + sub);
            float e1 = __shfl(el, k + 4 + sub);
            uint4 h0 = H16[(long)s0 * 16 + fc];
            uint4 h1 = H16[(long)s1 * 16 + fc];
            a0 += e0 * bflo(h0.x); a1 += e0 * bfhi(h0.x);
            a2 += e0 * bflo(h0.y); a3 += e0 * bfhi(h0.y);
            a4 += e0 * bflo(h0.z); a5 += e0 * bfhi(h0.z);
            a6 += e0 * bflo(h0.w); a7 += e0 * bfhi(h0.w);
            a0 += e1 * bflo(h1.x); a1 += e1 * bfhi(h1.x);
            a2 += e1 * bflo(h1.y); a3 += e1 * bfhi(h1.y);
            a4 += e1 * bflo(h1.z); a5 += e1 * bfhi(h1.z);
            a6 += e1 * bflo(h1.w); a7 += e1 * bfhi(h1.w);
            ss += e0 + e1;
        }
        if (k < kend) {
            int s0 = __shfl(sl, k + sub);
            float e0 = __shfl(el, k + sub);
            uint4 h0 = H16[(long)s0 * 16 + fc];
            a0 += e0 * bflo(h0.x); a1 += e0 * bfhi(h0.x);
            a2 += e0 * bflo(h0.y); a3 += e0 * bfhi(h0.y);
            a4 += e0 * bflo(h0.z); a5 += e0 * bfhi(h0.z);
            a6 += e0 * bflo(h0.w); a7 += e0 * bfhi(h0.w);
            ss += e0;
        }
    }
    a0 += __shfl_xor(a0, 16); a0 += __shfl_xor(a0, 32);
    a1 += __shfl_xor(a1, 16); a1 += __shfl_xor(a1, 32);
    a2 += __shfl_xor(a2, 16); a2 += __shfl_xor(a2, 32);
    a3 += __shfl_xor(a3, 16); a3 += __shfl_xor(a3, 32);
    a4 += __shfl_xor(a4, 16); a4 += __shfl_xor(a4, 32);
    a5 += __shfl_xor(a5, 16); a5 += __shfl_xor(a5, 32);
    a6 += __shfl_xor(a6, 16); a6 += __shfl_xor(a6, 32);
    a7 += __shfl_xor(a7, 16); a7 += __shfl_xor(a7, 32);
    ss += __shfl_xor(ss, 16); ss += __shfl_xor(ss, 32);
    // all lanes compute elu'd outputs for their chunk (needed for sub-split FC)
    float inv = 1.f / ss;
    const float4* b4 = (const float4*)bias;
    float4 bA = b4[fc * 2], bB = b4[fc * 2 + 1];
    float o0 = a0 * inv + bA.x, o1 = a1 * inv + bA.y;
    float o2 = a2 * inv + bA.z, o3 = a3 * inv + bA.w;
    float o4 = a4 * inv + bB.x, o5 = a5 * inv + bB.y;
    float o6 = a6 * inv + bB.z, o7 = a7 * inv + bB.w;
    o0 = o0 > 0.f ? o0 : expm1f(o0); o1 = o1 > 0.f ? o1 : expm1f(o1);
    o2 = o2 > 0.f ? o2 : expm1f(o2); o3 = o3 > 0.f ? o3 : expm1f(o3);
    o4 = o4 > 0.f ? o4 : expm1f(o4); o5 = o5 > 0.f ? o5 : expm1f(o5);
    o6 = o6 > 0.f ? o6 : expm1f(o6); o7 = o7 > 0.f ? o7 : expm1f(o7);
    if (sub == 0) {
        float4* o4p = (float4*)out;
        o4p[fc * 2] = make_float4(o0, o1, o2, o3);
        o4p[fc * 2 + 1] = make_float4(o4, o5, o6, o7);
    }
    if (isFull) {  // fused FC: sub s computes classes 4s..4s+3 over this lane's 8 features
        const float4* fW4 = (const float4*)fcW;
        int rb = (8 * fc) * 4 + sub;
        float4 w0 = fW4[rb], w1 = fW4[rb + 4], w2 = fW4[rb + 8], w3 = fW4[rb + 12];
        float4 w4 = fW4[rb + 16], w5 = fW4[rb + 20], w6 = fW4[rb + 24], w7 = fW4[rb + 28];
        float4 p;
        p.x = o0 * w0.x + o1 * w1.x + o2 * w2.x + o3 * w3.x +
              o4 * w4.x + o5 * w5.x + o6 * w6.x + o7 * w7.x;
        p.y = o0 * w0.y + o1 * w1.y + o2 * w2.y + o3 * w3.y +
              o4 * w4.y + o5 * w5.y + o6 * w6.y + o7 * w7.y;
        p.z = o0 * w0.z + o1 * w1.z + o2 * w2.z + o3 * w3.z +
              o4 * w4.z + o5 * w5.z + o6 * w6.z + o7 * w7.z;
        p.w = o0 * w0.w + o1 * w1.w + o2 * w2.w + o3 * w3.w +
              o4 * w4.w + o5 * w5.w + o6 * w6.w + o7 * w7.w;
        #pragma unroll
        for (int mask = 8; mask; mask >>= 1) {
            p.x += __shfl_xor(p.x, mask);
            p.y += __shfl_xor(p.y, mask);
            p.z += __shfl_xor(p.z, mask);
            p.w += __shfl_xor(p.w, mask);
        }
        if (fc == 0) ((float4*)(fxW + (long)w * 16))[sub] = p;
    }
}

// ---------------- adjacent-group sum (atomics; tiny graph) ----------------
__global__ __launch_bounds__(256) void adj_kernel(const int* __restrict__ gsrc,
                                                  const int* __restrict__ gdst, int Eg,
                                                  const float* __restrict__ gx,
                                                  float* __restrict__ adj_sum,
                                                  float* __restrict__ cnt) {
    int gid = blockIdx.x * 256 + threadIdx.x;
    int i = gid >> 6, lane = gid & 63;
    if (i >= Eg) return;
    int s = gsrc[i], d = gdst[i];
    float2 gv = ((const float2*)gx)[(long)d * 64 + lane];
    atomicAdd(&adj_sum[(long)s * 128 + 2 * lane], gv.x);
    atomicAdd(&adj_sum[(long)s * 128 + 2 * lane + 1], gv.y);
    if (lane == 0) atomicAdd(&cnt[s], 1.f);
}

// ---- per-group: adj_mean row + FC projections gfW = gx@fcW, amW = adj_mean@fcW ----
__global__ __launch_bounds__(256) void groupfc_kernel(const float* __restrict__ gx,
                                                      const float* __restrict__ adj_sum,
                                                      const float* __restrict__ cnt,
                                                      const float* __restrict__ fcW,
                                                      float* __restrict__ adj_mean,
                                                      float* __restrict__ gfW,
                                                      float* __restrict__ amW, int G) {
    int gid = blockIdx.x * 256 + threadIdx.x;
    int g = gid >> 6, lane = gid & 63;
    if (g >= G) return;
    float inv = 1.f / fmaxf(cnt[g], 1.f);
    float2 as2 = ((const float2*)adj_sum)[(long)g * 64 + lane];
    float2 am = make_float2(as2.x * inv, as2.y * inv);
    ((float2*)adj_mean)[(long)g * 64 + lane] = am;
    float2 gf = ((const float2*)gx)[(long)g * 64 + lane];
    const float4* fW4 = (const float4*)fcW;
    float rg = fc_reduce16(gf.x, gf.y, lane, fW4);
    float ra = fc_reduce16(am.x, am.y, lane, fW4);
    int cls = (lane >> 2) & 15;
    if ((lane & 3) == 0) {
        gfW[(long)g * 16 + cls] = rg;
        amW[(long)g * 16 + cls] = ra;
    }
}

// ---- final: dots + in-place updated; out via precomputed projections (no matvec) ----
__global__ __launch_bounds__(256) void final3_kernel(const int* __restrict__ node_group,
                                                     const float* __restrict__ gx,
                                                     const float* __restrict__ adj_mean,
                                                     const float* __restrict__ gfW,
                                                     const float* __restrict__ amW,
                                                     const float* __restrict__ fxW,
                                                     const float* __restrict__ fcb,
                                                     float* __restrict__ upd,
                                                     float* __restrict__ out, int N) {
    int gid = blockIdx.x * 256 + threadIdx.x;
    int n = gid >> 6, lane = gid & 63;
    if (n >= N) return;
    int g = node_group[n];
    float2 row = ((const float2*)upd)[(long)n * 64 + lane];
    float2 gf = ((const float2*)gx)[(long)g * 64 + lane];
    float2 am = ((const float2*)adj_mean)[(long)g * 64 + lane];
    float pg = row.x * gf.x + row.y * gf.y;
    float pa = row.x * am.x + row.y * am.y;
    #pragma unroll
    for (int off = 32; off; off >>= 1) {
        pg += __shfl_xor(pg, off);
        pa += __shfl_xor(pa, off);
    }
    float ux = row.x + pg * gf.x + pa * am.x;
    float uy = row.y + pg * gf.y + pa * am.y;
    ((float2*)upd)[(long)n * 64 + lane] = make_float2(ux, uy);
    if (lane < 16) {
        out[(long)n * 16 + lane] = fxW[(long)n * 16 + lane] + pg * gfW[(long)g * 16 + lane] +
                                   pa * amW[(long)g * 16 + lane] + fcb[lane];
    }
}

extern "C" void kernel_launch(void* const* d_in, const int* in_sizes, int n_in,
                              void* d_out, int out_size, void* d_ws, size_t ws_size,
                              hipStream_t stream) {
    const float* x_full = (const float*)d_in[0];
    const float* x_group = (const float*)d_in[1];
    const float* W_full = (const float*)d_in[2];
    const float* a_src_full = (const float*)d_in[3];
    const float* a_dst_full = (const float*)d_in[4];
    const float* bias_full = (const float*)d_in[5];
    const float* W_group = (const float*)d_in[6];
    const float* a_src_g = (const float*)d_in[7];
    const float* a_dst_g = (const float*)d_in[8];
    const float* bias_g = (const float*)d_in[9];
    const float* fc_W = (const float*)d_in[10];
    const float* fc_b = (const float*)d_in[11];
    const int* ef = (const int*)d_in[12];
    const int* eg = (const int*)d_in[13];
    const int* node_group = (const int*)d_in[14];

    int N = in_sizes[0] / 128;
    int G = in_sizes[1] / 128;
    int E = in_sizes[12] / 2;
    int Eg = in_sizes[13] / 2;
    const int* ef_src = ef;
    const int* ef_dst = ef + E;
    const int* eg_src = eg;
    const int* eg_dst = eg + Eg;

    int Npad = (N + 255) & ~255;
    int Ltot = Npad + G;
    int LtotPad = (Ltot + 255) & ~255;
    int totF = E + N;
    int tot = totF + Eg + G;

    float* out_cls = (float*)d_out;
    float* fx = out_cls + (long)N * 16;  // fullx_elu scratch, becomes `updated`

    char* w = (char*)d_ws;
    auto alloc = [&](size_t bytes) {
        char* p = w;
        w += (bytes + 255) & ~(size_t)255;
        return p;
    };
    u16* h_full = (u16*)alloc((size_t)N * 128 * 2);
    u16* h_g = (u16*)alloc((size_t)G * 128 * 2);
    float* a_s = (float*)alloc((size_t)N * 4);
    float* a_d = (float*)alloc((size_t)N * 4);
    float* a_sg = (float*)alloc((size_t)G * 4);
    float* a_dg = (float*)alloc((size_t)G * 4);
    float* gx = (float*)alloc((size_t)G * 128 * 4);
    float* adj_mean = (float*)alloc((size_t)G * 128 * 4);
    float* fxW = (float*)alloc((size_t)N * 16 * 4);
    float* gfW = (float*)alloc((size_t)G * 16 * 4);
    float* amW = (float*)alloc((size_t)G * 16 * 4);
    // zero-init span: adj_sum, cnt, deg (contiguous, one memset)
    float* adj_sum = (float*)alloc((size_t)G * 128 * 4);
    float* cnt = (float*)alloc((size_t)G * 4);
    int* deg = (int*)alloc((size_t)LtotPad * 4);
    int* offs = (int*)alloc((size_t)(LtotPad + 1) * 4);
    int2* sepack = (int2*)alloc((size_t)tot * 8);
    int* bsum = (int*)alloc(256 * 4);

    size_t zero_span = (char*)(deg + LtotPad) - (char*)adj_sum;
    (void)hipMemsetAsync(adj_sum, 0, zero_span, stream);

    auto cdiv = [](int a, int b) { return (a + b - 1) / b; };

    // GEMM (both graphs) + histogram, one launch (independent block roles)
    int nbFull = cdiv(N, 32);
    int nbGemm = nbFull + cdiv(G, 32);
    int nbHist = cdiv(tot, 256);
    gemm_hist_kernel<<<nbGemm + nbHist, 256, 0, stream>>>(
        x_full, W_full, a_src_full, a_dst_full, h_full, a_s, a_d, N,
        x_group, W_group, a_src_g, a_dst_g, h_g, a_sg, a_dg, G,
        nbFull, nbGemm, ef_dst, E, eg_dst, Eg, Npad, deg);

    // CSR scan + placement
    int nb = cdiv(Ltot, 256);
    scan1_kernel<<<nb, 256, 0, stream>>>(deg, Ltot, bsum);
    scan3_kernel<<<nb, 256, 0, stream>>>(deg, Ltot, nb, bsum, offs, Ltot);
    place2_kernel<<<cdiv(tot, 256), 256, 0, stream>>>(ef_src, ef_dst, E, N, eg_src, eg_dst,
                                                      Eg, G, Npad, a_s, a_d, a_sg, a_dg,
                                                      deg, sepack);

    // pull aggregation (both graphs) + fused fxW projection
    pull2_kernel<<<cdiv((N + G) * 64, 256), 256, 0, stream>>>(h_full, h_g, offs, sepack,
                                                              bias_full, bias_g, fc_W,
                                                              fx, gx, fxW, N, G, Npad);

    // adjacent-group sum -> per-group mean + FC projections -> slim final
    adj_kernel<<<cdiv(Eg * 64, 256), 256, 0, stream>>>(eg_src, eg_dst, Eg, gx, adj_sum, cnt);
    groupfc_kernel<<<cdiv(G * 64, 256), 256, 0, stream>>>(gx, adj_sum, cnt, fc_W,
                                                          adj_mean, gfW, amW, G);
    final3_kernel<<<cdiv(N * 64, 256), 256, 0, stream>>>(node_group, gx, adj_mean, gfW, amW,
                                                         fxW, fc_b, fx, out_cls, N);
}

// Round 11
// 274.423 us; speedup vs baseline: 1.0771x; 1.0296x over previous
//
#include <hip/hip_runtime.h>

typedef unsigned short u16;
typedef unsigned int u32;

static __device__ __forceinline__ float lrelu(float x) { return x >= 0.f ? x : 0.2f * x; }

static __device__ __forceinline__ u16 f2bf(float f) {
    u32 u = __float_as_uint(f);
    u += 0x7FFF + ((u >> 16) & 1);
    return (u16)(u >> 16);
}
static __device__ __forceinline__ float bflo(u32 u) { return __uint_as_float(u << 16); }
static __device__ __forceinline__ float bfhi(u32 u) { return __uint_as_float(u & 0xffff0000u); }

// ---- merged: GEMM (both graphs, blocks [0,nbGemm)) + edge histogram (rest) ----
__global__ __launch_bounds__(256) void gemm_hist_kernel(
        const float* __restrict__ Xf, const float* __restrict__ Wf,
        const float* __restrict__ asf, const float* __restrict__ adf,
        u16* __restrict__ Hbf, float* __restrict__ as_f, float* __restrict__ ad_f, int N,
        const float* __restrict__ Xg, const float* __restrict__ Wg,
        const float* __restrict__ asg, const float* __restrict__ adg,
        u16* __restrict__ Hbg, float* __restrict__ as_g, float* __restrict__ ad_g, int G,
        int nbFull, int nbGemm,
        const int* __restrict__ efd, int E, const int* __restrict__ egd, int Eg,
        int Npad, int* __restrict__ deg) {
    __shared__ float Ws[64 * 128];
    __shared__ float Xs[32 * 128];
    int tid = threadIdx.x;
    if (blockIdx.x >= nbGemm) {
        int i = (blockIdx.x - nbGemm) * 256 + tid;
        int totF = E + N;
        int tot = totF + Eg + G;
        if (i >= tot) return;
        int d;
        if (i < E) d = efd[i];
        else if (i < totF) d = i - E;
        else {
            int j = i - totF;
            d = Npad + ((j < Eg) ? egd[j] : (j - Eg));
        }
        atomicAdd(&deg[d], 1);
        return;
    }
    const float* X; const float* W; const float* av; const float* dv;
    u16* Hb; float* as_out; float* ad_out; int n_lim; long base;
    if (blockIdx.x < nbFull) {
        X = Xf; W = Wf; av = asf; dv = adf; Hb = Hbf; as_out = as_f; ad_out = ad_f;
        n_lim = N; base = (long)blockIdx.x * 32;
    } else {
        X = Xg; W = Wg; av = asg; dv = adg; Hb = Hbg; as_out = as_g; ad_out = ad_g;
        n_lim = G; base = (long)(blockIdx.x - nbFull) * 32;
    }
    float4* Ws4 = (float4*)Ws;
    float4* Xs4 = (float4*)Xs;
    const float4* X4 = (const float4*)(X + base * 128);
    for (int i = tid; i < 1024; i += 256) {
        int r = i >> 5;
        Xs4[i] = (base + r < n_lim) ? X4[i] : make_float4(0.f, 0.f, 0.f, 0.f);
    }
    int fgrp = tid & 31;
    int n0 = (tid >> 5) * 4;
    float4 acc[4] = {};
    for (int half = 0; half < 2; ++half) {
        __syncthreads();
        const float4* W4 = (const float4*)(W + half * 64 * 128);
        for (int i = tid; i < 2048; i += 256) Ws4[i] = W4[i];
        __syncthreads();
        #pragma unroll 4
        for (int kk = 0; kk < 64; ++kk) {
            float4 w = Ws4[kk * 32 + fgrp];
            #pragma unroll
            for (int j = 0; j < 4; ++j) {
                float x = Xs[(n0 + j) * 128 + half * 64 + kk];
                acc[j].x += x * w.x; acc[j].y += x * w.y;
                acc[j].z += x * w.z; acc[j].w += x * w.w;
            }
        }
    }
    float4 as4 = ((const float4*)av)[fgrp];
    float4 ad4 = ((const float4*)dv)[fgrp];
    float ps[4], pd[4];
    #pragma unroll
    for (int j = 0; j < 4; ++j) {
        ps[j] = acc[j].x * as4.x + acc[j].y * as4.y + acc[j].z * as4.z + acc[j].w * as4.w;
        pd[j] = acc[j].x * ad4.x + acc[j].y * ad4.y + acc[j].z * ad4.z + acc[j].w * ad4.w;
    }
    #pragma unroll
    for (int off = 16; off; off >>= 1) {
        #pragma unroll
        for (int j = 0; j < 4; ++j) {
            ps[j] += __shfl_xor(ps[j], off);
            pd[j] += __shfl_xor(pd[j], off);
        }
    }
    if ((tid & 31) == 0) {
        #pragma unroll
        for (int j = 0; j < 4; ++j) {
            long n = base + n0 + j;
            if (n < n_lim) { as_out[n] = ps[j]; ad_out[n] = pd[j]; }
        }
    }
    #pragma unroll
    for (int j = 0; j < 4; ++j) {
        long n = base + n0 + j;
        if (n < n_lim) {
            ushort4 hv;
            hv.x = f2bf(acc[j].x); hv.y = f2bf(acc[j].y);
            hv.z = f2bf(acc[j].z); hv.w = f2bf(acc[j].w);
            ((ushort4*)(Hb + n * 128))[fgrp] = hv;
        }
    }
}

__global__ __launch_bounds__(256) void scan1_kernel(const int* __restrict__ deg, int n,
                                                    int* __restrict__ bsum) {
    __shared__ int s[256];
    int i = blockIdx.x * 256 + threadIdx.x;
    s[threadIdx.x] = (i < n) ? deg[i] : 0;
    __syncthreads();
    for (int off = 128; off; off >>= 1) {
        if (threadIdx.x < off) s[threadIdx.x] += s[threadIdx.x + off];
        __syncthreads();
    }
    if (threadIdx.x == 0) bsum[blockIdx.x] = s[0];
}

__global__ __launch_bounds__(256) void scan3_kernel(int* __restrict__ deg, int n, int nb,
                                                    const int* __restrict__ bsum,
                                                    int* __restrict__ offs, int Ltot) {
    __shared__ int sb[256];
    __shared__ int s[256];
    int t = threadIdx.x;
    sb[t] = (t < nb) ? bsum[t] : 0;
    __syncthreads();
    for (int off = 1; off < 256; off <<= 1) {
        int u = (t >= off) ? sb[t - off] : 0;
        __syncthreads();
        sb[t] += u;
        __syncthreads();
    }
    int blockOff = (blockIdx.x == 0) ? 0 : sb[blockIdx.x - 1];
    if (blockIdx.x == 0 && t == 0) offs[Ltot] = sb[nb - 1];

    int i = blockIdx.x * 256 + t;
    int v = (i < n) ? deg[i] : 0;
    s[t] = v;
    __syncthreads();
    for (int off = 1; off < 256; off <<= 1) {
        int u = (t >= off) ? s[t - off] : 0;
        __syncthreads();
        s[t] += u;
        __syncthreads();
    }
    if (i < n) {
        int excl = s[t] - v + blockOff;
        offs[i] = excl;
        deg[i] = excl;
    }
}

// placement: packed (src, e) per edge; e = exp(lrelu(a_s[src]+a_d[dst])) computed ONCE
__global__ __launch_bounds__(256) void place2_kernel(const int* __restrict__ efs,
                                                     const int* __restrict__ efd, int E, int N,
                                                     const int* __restrict__ egs,
                                                     const int* __restrict__ egd, int Eg, int G,
                                                     int Npad,
                                                     const float* __restrict__ a_s,
                                                     const float* __restrict__ a_d,
                                                     const float* __restrict__ a_sg,
                                                     const float* __restrict__ a_dg,
                                                     int* __restrict__ cursor,
                                                     int2* __restrict__ sepack) {
    int i = blockIdx.x * 256 + threadIdx.x;
    int totF = E + N;
    int tot = totF + Eg + G;
    if (i >= tot) return;
    int s, d, dcur;
    float av;
    if (i < totF) {
        if (i < E) { s = efs[i]; d = efd[i]; } else { s = d = i - E; }
        av = a_s[s] + a_d[d];
        dcur = d;
    } else {
        int j = i - totF;
        if (j < Eg) { s = egs[j]; d = egd[j]; } else { s = d = j - Eg; }
        av = a_sg[s] + a_dg[d];
        dcur = Npad + d;
    }
    float e = expf(lrelu(av));  // max-subtract skipped: alpha identical, no overflow
    int pos = atomicAdd(&cursor[dcur], 1);
    sepack[pos] = make_int2(s, __float_as_int(e));
}

// gather-aggregate core: 16B/lane (lane = edge subset sub=l>>4, feature chunk fc=l&15).
// Pad edges carry e=0. Returns per-lane chunk totals a0..a7 and weight sum ss
// (valid in every lane after the 16/32 combine).
#define PULL_GATHER_BODY(H16, beg, end)                                          \
    for (int b = (beg); b < (end); b += 64) {                                    \
        int m = (end) - b;                                                       \
        if (m > 64) m = 64;                                                      \
        int2 se = (lane < m) ? sepack[b + lane] : make_int2(0, 0);               \
        int sl = se.x;                                                           \
        float el = __int_as_float(se.y);                                         \
        int kend = (m + 3) & ~3;                                                 \
        int k = 0;                                                               \
        for (; k + 16 <= kend; k += 16) {                                        \
            int s0 = __shfl(sl, k + sub);                                        \
            float e0 = __shfl(el, k + sub);                                      \
            int s1 = __shfl(sl, k + 4 + sub);                                    \
            float e1 = __shfl(el, k + 4 + sub);                                  \
            int s2 = __shfl(sl, k + 8 + sub);                                    \
            float e2 = __shfl(el, k + 8 + sub);                                  \
            int s3 = __shfl(sl, k + 12 + sub);                                   \
            float e3 = __shfl(el, k + 12 + sub);                                 \
            uint4 h0 = H16[(long)s0 * 16 + fc];                                  \
            uint4 h1 = H16[(long)s1 * 16 + fc];                                  \
            uint4 h2 = H16[(long)s2 * 16 + fc];                                  \
            uint4 h3 = H16[(long)s3 * 16 + fc];                                  \
            a0 += e0 * bflo(h0.x); a1 += e0 * bfhi(h0.x);                        \
            a2 += e0 * bflo(h0.y); a3 += e0 * bfhi(h0.y);                        \
            a4 += e0 * bflo(h0.z); a5 += e0 * bfhi(h0.z);                        \
            a6 += e0 * bflo(h0.w); a7 += e0 * bfhi(h0.w);                        \
            a0 += e1 * bflo(h1.x); a1 += e1 * bfhi(h1.x);                        \
            a2 += e1 * bflo(h1.y); a3 += e1 * bfhi(h1.y);                        \
            a4 += e1 * bflo(h1.z); a5 += e1 * bfhi(h1.z);                        \
            a6 += e1 * bflo(h1.w); a7 += e1 * bfhi(h1.w);                        \
            a0 += e2 * bflo(h2.x); a1 += e2 * bfhi(h2.x);                        \
            a2 += e2 * bflo(h2.y); a3 += e2 * bfhi(h2.y);                        \
            a4 += e2 * bflo(h2.z); a5 += e2 * bfhi(h2.z);                        \
            a6 += e2 * bflo(h2.w); a7 += e2 * bfhi(h2.w);                        \
            a0 += e3 * bflo(h3.x); a1 += e3 * bfhi(h3.x);                        \
            a2 += e3 * bflo(h3.y); a3 += e3 * bfhi(h3.y);                        \
            a4 += e3 * bflo(h3.z); a5 += e3 * bfhi(h3.z);                        \
            a6 += e3 * bflo(h3.w); a7 += e3 * bfhi(h3.w);                        \
            ss += (e0 + e1) + (e2 + e3);                                         \
        }                                                                        \
        for (; k + 8 <= kend; k += 8) {                                          \
            int s0 = __shfl(sl, k + sub);                                        \
            float e0 = __shfl(el, k + sub);                                      \
            int s1 = __shfl(sl, k + 4 + sub);                                    \
            float e1 = __shfl(el, k + 4 + sub);                                  \
            uint4 h0 = H16[(long)s0 * 16 + fc];                                  \
            uint4 h1 = H16[(long)s1 * 16 + fc];                                  \
            a0 += e0 * bflo(h0.x); a1 += e0 * bfhi(h0.x);                        \
            a2 += e0 * bflo(h0.y); a3 += e0 * bfhi(h0.y);                        \
            a4 += e0 * bflo(h0.z); a5 += e0 * bfhi(h0.z);                        \
            a6 += e0 * bflo(h0.w); a7 += e0 * bfhi(h0.w);                        \
            a0 += e1 * bflo(h1.x); a1 += e1 * bfhi(h1.x);                        \
            a2 += e1 * bflo(h1.y); a3 += e1 * bfhi(h1.y);                        \
            a4 += e1 * bflo(h1.z); a5 += e1 * bfhi(h1.z);                        \
            a6 += e1 * bflo(h1.w); a7 += e1 * bfhi(h1.w);                        \
            ss += e0 + e1;                                                       \
        }                                                                        \
        if (k < kend) {                                                          \
            int s0 = __shfl(sl, k + sub);                                        \
            float e0 = __shfl(el, k + sub);                                      \
            uint4 h0 = H16[(long)s0 * 16 + fc];                                  \
            a0 += e0 * bflo(h0.x); a1 += e0 * bfhi(h0.x);                        \
            a2 += e0 * bflo(h0.y); a3 += e0 * bfhi(h0.y);                        \
            a4 += e0 * bflo(h0.z); a5 += e0 * bfhi(h0.z);                        \
            a6 += e0 * bflo(h0.w); a7 += e0 * bfhi(h0.w);                        \
            ss += e0;                                                            \
        }                                                                        \
    }                                                                            \
    a0 += __shfl_xor(a0, 16); a0 += __shfl_xor(a0, 32);                          \
    a1 += __shfl_xor(a1, 16); a1 += __shfl_xor(a1, 32);                          \
    a2 += __shfl_xor(a2, 16); a2 += __shfl_xor(a2, 32);                          \
    a3 += __shfl_xor(a3, 16); a3 += __shfl_xor(a3, 32);                          \
    a4 += __shfl_xor(a4, 16); a4 += __shfl_xor(a4, 32);                          \
    a5 += __shfl_xor(a5, 16); a5 += __shfl_xor(a5, 32);                          \
    a6 += __shfl_xor(a6, 16); a6 += __shfl_xor(a6, 32);                          \
    a7 += __shfl_xor(a7, 16); a7 += __shfl_xor(a7, 32);                          \
    ss += __shfl_xor(ss, 16); ss += __shfl_xor(ss, 32);

// ---- group pull: gx = elu(sum(e*h)/sum(e) + bias_g), 512 waves ----
__global__ __launch_bounds__(256) void pull_g_kernel(const u16* __restrict__ Hg,
                                                     const int* __restrict__ offs,
                                                     const int2* __restrict__ sepack,
                                                     const float* __restrict__ bias_g,
                                                     float* __restrict__ gx,
                                                     int G, int Npad) {
    int gid = blockIdx.x * 256 + threadIdx.x;
    int w = gid >> 6, lane = gid & 63;
    if (w >= G) return;
    int idx = Npad + w;
    int beg = offs[idx], end = offs[idx + 1];
    const uint4* H16 = (const uint4*)Hg;
    int sub = lane >> 4;
    int fc = lane & 15;
    float a0 = 0.f, a1 = 0.f, a2 = 0.f, a3 = 0.f;
    float a4 = 0.f, a5 = 0.f, a6 = 0.f, a7 = 0.f;
    float ss = 0.f;
    PULL_GATHER_BODY(H16, beg, end)
    if (sub == 0) {
        float inv = 1.f / ss;
        const float4* b4 = (const float4*)bias_g;
        float4 bA = b4[fc * 2], bB = b4[fc * 2 + 1];
        float o0 = a0 * inv + bA.x, o1 = a1 * inv + bA.y;
        float o2 = a2 * inv + bA.z, o3 = a3 * inv + bA.w;
        float o4 = a4 * inv + bB.x, o5 = a5 * inv + bB.y;
        float o6 = a6 * inv + bB.z, o7 = a7 * inv + bB.w;
        o0 = o0 > 0.f ? o0 : expm1f(o0); o1 = o1 > 0.f ? o1 : expm1f(o1);
        o2 = o2 > 0.f ? o2 : expm1f(o2); o3 = o3 > 0.f ? o3 : expm1f(o3);
        o4 = o4 > 0.f ? o4 : expm1f(o4); o5 = o5 > 0.f ? o5 : expm1f(o5);
        o6 = o6 > 0.f ? o6 : expm1f(o6); o7 = o7 > 0.f ? o7 : expm1f(o7);
        float4* o4p = (float4*)(gx + (long)w * 128);
        o4p[fc * 2] = make_float4(o0, o1, o2, o3);
        o4p[fc * 2 + 1] = make_float4(o4, o5, o6, o7);
    }
}

// ---------------- adjacent-group sum (atomics; tiny graph) ----------------
__global__ __launch_bounds__(256) void adj_kernel(const int* __restrict__ gsrc,
                                                  const int* __restrict__ gdst, int Eg,
                                                  const float* __restrict__ gx,
                                                  float* __restrict__ adj_sum,
                                                  float* __restrict__ cnt) {
    int gid = blockIdx.x * 256 + threadIdx.x;
    int i = gid >> 6, lane = gid & 63;
    if (i >= Eg) return;
    int s = gsrc[i], d = gdst[i];
    float2 gv = ((const float2*)gx)[(long)d * 64 + lane];
    atomicAdd(&adj_sum[(long)s * 128 + 2 * lane], gv.x);
    atomicAdd(&adj_sum[(long)s * 128 + 2 * lane + 1], gv.y);
    if (lane == 0) atomicAdd(&cnt[s], 1.f);
}

// ---- full pull + interaction + FC, all fused (fx never leaves registers) ----
__global__ __launch_bounds__(256) void pull_f_final_kernel(
        const u16* __restrict__ Hf,
        const int* __restrict__ offs,
        const int2* __restrict__ sepack,
        const float* __restrict__ bias_f,
        const int* __restrict__ node_group,
        const float* __restrict__ gx,
        const float* __restrict__ adj_sum,
        const float* __restrict__ cnt,
        const float* __restrict__ fcW,
        const float* __restrict__ fcb,
        float* __restrict__ upd,
        float* __restrict__ out, int N) {
    int gid = blockIdx.x * 256 + threadIdx.x;
    int w = gid >> 6, lane = gid & 63;
    if (w >= N) return;
    int beg = offs[w], end = offs[w + 1];
    const uint4* H16 = (const uint4*)Hf;
    int sub = lane >> 4;
    int fc = lane & 15;
    float a0 = 0.f, a1 = 0.f, a2 = 0.f, a3 = 0.f;
    float a4 = 0.f, a5 = 0.f, a6 = 0.f, a7 = 0.f;
    float ss = 0.f;
    PULL_GATHER_BODY(H16, beg, end)
    // elu'd fx chunk in registers (all lanes, duplicated across subs)
    float inv = 1.f / ss;
    const float4* b4 = (const float4*)bias_f;
    float4 bA = b4[fc * 2], bB = b4[fc * 2 + 1];
    float o0 = a0 * inv + bA.x, o1 = a1 * inv + bA.y;
    float o2 = a2 * inv + bA.z, o3 = a3 * inv + bA.w;
    float o4 = a4 * inv + bB.x, o5 = a5 * inv + bB.y;
    float o6 = a6 * inv + bB.z, o7 = a7 * inv + bB.w;
    o0 = o0 > 0.f ? o0 : expm1f(o0); o1 = o1 > 0.f ? o1 : expm1f(o1);
    o2 = o2 > 0.f ? o2 : expm1f(o2); o3 = o3 > 0.f ? o3 : expm1f(o3);
    o4 = o4 > 0.f ? o4 : expm1f(o4); o5 = o5 > 0.f ? o5 : expm1f(o5);
    o6 = o6 > 0.f ? o6 : expm1f(o6); o7 = o7 > 0.f ? o7 : expm1f(o7);
    // interaction: gather group rows (L2-resident), dots via 16-lane reduce
    int g = node_group[w];
    const float4* gx4 = (const float4*)(gx + (long)g * 128);
    const float4* am4 = (const float4*)(adj_sum + (long)g * 128);
    float inv_cnt = 1.f / fmaxf(cnt[g], 1.f);
    float4 gfA = gx4[fc * 2], gfB = gx4[fc * 2 + 1];
    float4 amA = am4[fc * 2], amB = am4[fc * 2 + 1];
    amA.x *= inv_cnt; amA.y *= inv_cnt; amA.z *= inv_cnt; amA.w *= inv_cnt;
    amB.x *= inv_cnt; amB.y *= inv_cnt; amB.z *= inv_cnt; amB.w *= inv_cnt;
    float pg = o0 * gfA.x + o1 * gfA.y + o2 * gfA.z + o3 * gfA.w +
               o4 * gfB.x + o5 * gfB.y + o6 * gfB.z + o7 * gfB.w;
    float pa = o0 * amA.x + o1 * amA.y + o2 * amA.z + o3 * amA.w +
               o4 * amB.x + o5 * amB.y + o6 * amB.z + o7 * amB.w;
    #pragma unroll
    for (int mask = 8; mask; mask >>= 1) {
        pg += __shfl_xor(pg, mask);
        pa += __shfl_xor(pa, mask);
    }
    // updated chunk in registers
    float u0 = o0 + pg * gfA.x + pa * amA.x;
    float u1 = o1 + pg * gfA.y + pa * amA.y;
    float u2 = o2 + pg * gfA.z + pa * amA.z;
    float u3 = o3 + pg * gfA.w + pa * amA.w;
    float u4 = o4 + pg * gfB.x + pa * amB.x;
    float u5 = o5 + pg * gfB.y + pa * amB.y;
    float u6 = o6 + pg * gfB.z + pa * amB.z;
    float u7 = o7 + pg * gfB.w + pa * amB.w;
    if (sub == 0) {
        float4* o4p = (float4*)(upd + (long)w * 128);
        o4p[fc * 2] = make_float4(u0, u1, u2, u3);
        o4p[fc * 2 + 1] = make_float4(u4, u5, u6, u7);
    }
    // FC: sub s computes classes 4s..4s+3 over this lane's 8 features
    const float4* fW4 = (const float4*)fcW;
    int rb = (8 * fc) * 4 + sub;
    float4 w0 = fW4[rb], w1 = fW4[rb + 4], w2 = fW4[rb + 8], w3 = fW4[rb + 12];
    float4 w4 = fW4[rb + 16], w5 = fW4[rb + 20], w6 = fW4[rb + 24], w7 = fW4[rb + 28];
    float4 p;
    p.x = u0 * w0.x + u1 * w1.x + u2 * w2.x + u3 * w3.x +
          u4 * w4.x + u5 * w5.x + u6 * w6.x + u7 * w7.x;
    p.y = u0 * w0.y + u1 * w1.y + u2 * w2.y + u3 * w3.y +
          u4 * w4.y + u5 * w5.y + u6 * w6.y + u7 * w7.y;
    p.z = u0 * w0.z + u1 * w1.z + u2 * w2.z + u3 * w3.z +
          u4 * w4.z + u5 * w5.z + u6 * w6.z + u7 * w7.z;
    p.w = u0 * w0.w + u1 * w1.w + u2 * w2.w + u3 * w3.w +
          u4 * w4.w + u5 * w5.w + u6 * w6.w + u7 * w7.w;
    #pragma unroll
    for (int mask = 8; mask; mask >>= 1) {
        p.x += __shfl_xor(p.x, mask);
        p.y += __shfl_xor(p.y, mask);
        p.z += __shfl_xor(p.z, mask);
        p.w += __shfl_xor(p.w, mask);
    }
    if (fc == 0) {
        float4 bb = ((const float4*)fcb)[sub];
        p.x += bb.x; p.y += bb.y; p.z += bb.z; p.w += bb.w;
        ((float4*)(out + (long)w * 16))[sub] = p;
    }
}

extern "C" void kernel_launch(void* const* d_in, const int* in_sizes, int n_in,
                              void* d_out, int out_size, void* d_ws, size_t ws_size,
                              hipStream_t stream) {
    const float* x_full = (const float*)d_in[0];
    const float* x_group = (const float*)d_in[1];
    const float* W_full = (const float*)d_in[2];
    const float* a_src_full = (const float*)d_in[3];
    const float* a_dst_full = (const float*)d_in[4];
    const float* bias_full = (const float*)d_in[5];
    const float* W_group = (const float*)d_in[6];
    const float* a_src_g = (const float*)d_in[7];
    const float* a_dst_g = (const float*)d_in[8];
    const float* bias_g = (const float*)d_in[9];
    const float* fc_W = (const float*)d_in[10];
    const float* fc_b = (const float*)d_in[11];
    const int* ef = (const int*)d_in[12];
    const int* eg = (const int*)d_in[13];
    const int* node_group = (const int*)d_in[14];

    int N = in_sizes[0] / 128;
    int G = in_sizes[1] / 128;
    int E = in_sizes[12] / 2;
    int Eg = in_sizes[13] / 2;
    const int* ef_src = ef;
    const int* ef_dst = ef + E;
    const int* eg_src = eg;
    const int* eg_dst = eg + Eg;

    int Npad = (N + 255) & ~255;
    int Ltot = Npad + G;
    int LtotPad = (Ltot + 255) & ~255;
    int totF = E + N;
    int tot = totF + Eg + G;

    float* out_cls = (float*)d_out;
    float* upd = out_cls + (long)N * 16;  // `updated` output region

    char* w = (char*)d_ws;
    auto alloc = [&](size_t bytes) {
        char* p = w;
        w += (bytes + 255) & ~(size_t)255;
        return p;
    };
    u16* h_full = (u16*)alloc((size_t)N * 128 * 2);
    u16* h_g = (u16*)alloc((size_t)G * 128 * 2);
    float* a_s = (float*)alloc((size_t)N * 4);
    float* a_d = (float*)alloc((size_t)N * 4);
    float* a_sg = (float*)alloc((size_t)G * 4);
    float* a_dg = (float*)alloc((size_t)G * 4);
    float* gx = (float*)alloc((size_t)G * 128 * 4);
    // zero-init span: adj_sum, cnt, deg (contiguous, one memset)
    float* adj_sum = (float*)alloc((size_t)G * 128 * 4);
    float* cnt = (float*)alloc((size_t)G * 4);
    int* deg = (int*)alloc((size_t)LtotPad * 4);
    int* offs = (int*)alloc((size_t)(LtotPad + 1) * 4);
    int2* sepack = (int2*)alloc((size_t)tot * 8);
    int* bsum = (int*)alloc(256 * 4);

    size_t zero_span = (char*)(deg + LtotPad) - (char*)adj_sum;
    (void)hipMemsetAsync(adj_sum, 0, zero_span, stream);

    auto cdiv = [](int a, int b) { return (a + b - 1) / b; };

    // GEMM (both graphs) + histogram, one launch (independent block roles)
    int nbFull = cdiv(N, 32);
    int nbGemm = nbFull + cdiv(G, 32);
    int nbHist = cdiv(tot, 256);
    gemm_hist_kernel<<<nbGemm + nbHist, 256, 0, stream>>>(
        x_full, W_full, a_src_full, a_dst_full, h_full, a_s, a_d, N,
        x_group, W_group, a_src_g, a_dst_g, h_g, a_sg, a_dg, G,
        nbFull, nbGemm, ef_dst, E, eg_dst, Eg, Npad, deg);

    // CSR scan + placement
    int nb = cdiv(Ltot, 256);
    scan1_kernel<<<nb, 256, 0, stream>>>(deg, Ltot, bsum);
    scan3_kernel<<<nb, 256, 0, stream>>>(deg, Ltot, nb, bsum, offs, Ltot);
    place2_kernel<<<cdiv(tot, 256), 256, 0, stream>>>(ef_src, ef_dst, E, N, eg_src, eg_dst,
                                                      Eg, G, Npad, a_s, a_d, a_sg, a_dg,
                                                      deg, sepack);

    // group pull -> adjacent-group sum -> fused full pull + interaction + FC
    pull_g_kernel<<<cdiv(G * 64, 256), 256, 0, stream>>>(h_g, offs, sepack, bias_g,
                                                         gx, G, Npad);
    adj_kernel<<<cdiv(Eg * 64, 256), 256, 0, stream>>>(eg_src, eg_dst, Eg, gx, adj_sum, cnt);
    pull_f_final_kernel<<<cdiv(N * 64, 256), 256, 0, stream>>>(
        h_full, offs, sepack, bias_full, node_group, gx, adj_sum, cnt,
        fc_W, fc_b, upd, out_cls, N);
}